// Round 7
// baseline (634.780 us; speedup 1.0000x reference)
//
#include <hip/hip_runtime.h>
#include <hip/hip_bf16.h>
#include <cstddef>
#include <cstdint>

// Problem constants
#define NB 4
#define NL 1024
#define IN_DIM 64
#define D_MODEL 512
#define N_LAYERS 3
#define D_INNER 1024
#define NSTATE 16
#define DT_RANK 32
#define KCONV 4
#define NROWS (NB * NL)   // 4096
#define CHUNK 16
#define NCHUNK (NL / CHUNK)  // 64
#define LOG2E 1.4426950408889634f

typedef __attribute__((ext_vector_type(8))) short short8;
typedef __attribute__((ext_vector_type(4))) float f32x4;
typedef __attribute__((ext_vector_type(4))) unsigned short us4;
typedef unsigned short ushort_t;

// float -> bf16 round-to-nearest-even
__device__ __forceinline__ ushort_t f2b1(float x) {
  uint32_t u = __builtin_bit_cast(uint32_t, x);
  u += 0x7fffu + ((u >> 16) & 1u);
  return (ushort_t)(u >> 16);
}
__device__ __forceinline__ float b2f(ushort_t u) {
  return __builtin_bit_cast(float, (uint32_t)u << 16);
}

// async global->LDS, 16B per lane. dst is wave-uniform base; HW adds lane*16.
__device__ __forceinline__ void gload_lds16(const ushort_t* src, short* dst) {
  __builtin_amdgcn_global_load_lds(
      (const __attribute__((address_space(1))) uint32_t*)src,
      (__attribute__((address_space(3))) uint32_t*)dst, 16, 0, 0);
}

// ---------------------------------------------------------------------------
// Fused fp32 -> bf16 conversion of x + all weights (one dispatch).
// ---------------------------------------------------------------------------
#define E0 (NROWS * IN_DIM)                    // x        262144
#define E1 (D_MODEL * IN_DIM)                  // input_w   32768
#define E2 (N_LAYERS * 2 * D_INNER * D_MODEL)  // in_proj 3145728
#define E3 (N_LAYERS * 64 * D_INNER)           // x_proj   196608
#define E4 (N_LAYERS * D_INNER * DT_RANK)      // dt_proj   98304
#define E5 (N_LAYERS * D_MODEL * D_INNER)      // out_proj 1572864
#define ETOT (E0 + E1 + E2 + E3 + E4 + E5)     // 5308416

__global__ __launch_bounds__(256) void cvt_all(
    const float* __restrict__ x, const float* __restrict__ inw,
    const float* __restrict__ ipw, const float* __restrict__ xpw,
    const float* __restrict__ dpw, const float* __restrict__ opw,
    ushort_t* __restrict__ xb, ushort_t* __restrict__ inwb,
    ushort_t* __restrict__ iwb, ushort_t* __restrict__ xwb,
    ushort_t* __restrict__ dwb, ushort_t* __restrict__ owb)
{
  int i = (blockIdx.x * 256 + threadIdx.x) * 4;
  if (i >= ETOT) return;
  const float* src; ushort_t* dst; int off;
  if      (i < E0)                  { src = x;   dst = xb;   off = i; }
  else if (i < E0+E1)               { src = inw; dst = inwb; off = i - E0; }
  else if (i < E0+E1+E2)            { src = ipw; dst = iwb;  off = i - (E0+E1); }
  else if (i < E0+E1+E2+E3)         { src = xpw; dst = xwb;  off = i - (E0+E1+E2); }
  else if (i < E0+E1+E2+E3+E4)      { src = dpw; dst = dwb;  off = i - (E0+E1+E2+E3); }
  else                              { src = opw; dst = owb;  off = i - (E0+E1+E2+E3+E4); }
  const float4 v = *(const float4*)(src + off);
  us4 o;
  o.x = f2b1(v.x); o.y = f2b1(v.y); o.z = f2b1(v.z); o.w = f2b1(v.w);
  *(us4*)(dst + off) = o;
}

// ---------------------------------------------------------------------------
// bf16 MFMA GEMM, m97-style: global_load_lds staging, linear LDS [row][32],
// 2-barrier K-loop. C = A[M,lda] @ W[N,K]^T (+bias)(+softplus).
// 256 threads = 4 waves (2x2). BM=MF*32, BN=NF*32, K%32==0.
// ---------------------------------------------------------------------------
template<int BM, int BN, int MF, int NF, int ACT, bool WF32, bool WB16>
__global__ __launch_bounds__(256) void gemm_mfma(
    const ushort_t* __restrict__ A, int lda,
    const ushort_t* __restrict__ W,
    const float* __restrict__ bias,
    float* __restrict__ Cf, ushort_t* __restrict__ Cb,
    int M, int N, int K)
{
  constexpr int CA = BM / 64;
  constexpr int CB = BN / 64;
  __shared__ __align__(16) short sa[BM * 32];
  __shared__ __align__(16) short sb[BN * 32];

  const int tid = threadIdx.x;
  const int l = tid & 63;
  const int wid = tid >> 6;
  const int wrow = (wid >> 1) * (BM / 2);
  const int wcol = (wid & 1) * (BN / 2);
  const int m0 = blockIdx.y * BM;
  const int n0 = blockIdx.x * BN;

  const int srow = l >> 2;           // row within 16-row group
  const int scol = (l & 3) * 8;      // shorts (16B chunks)

  f32x4 acc[MF][NF] = {};

  for (int k0 = 0; k0 < K; k0 += 32) {
#pragma unroll
    for (int c = 0; c < CA; ++c) {
      short* dst = sa + (c * 4 + wid) * 512;   // wave-uniform, 1024B block
      const ushort_t* src =
          A + (size_t)(m0 + (c * 4 + wid) * 16 + srow) * lda + k0 + scol;
      gload_lds16(src, dst);
    }
#pragma unroll
    for (int c = 0; c < CB; ++c) {
      short* dst = sb + (c * 4 + wid) * 512;
      const ushort_t* src =
          W + (size_t)(n0 + (c * 4 + wid) * 16 + srow) * K + k0 + scol;
      gload_lds16(src, dst);
    }
    __syncthreads();   // drains vmcnt(0): tile in LDS, all waves synced

    short8 af[MF], bfr[NF];
#pragma unroll
    for (int mi = 0; mi < MF; ++mi)
      af[mi] = *(const short8*)(sa + (wrow + mi * 16 + (l & 15)) * 32 + (l >> 4) * 8);
#pragma unroll
    for (int nj = 0; nj < NF; ++nj)
      bfr[nj] = *(const short8*)(sb + (wcol + nj * 16 + (l & 15)) * 32 + (l >> 4) * 8);
#pragma unroll
    for (int mi = 0; mi < MF; ++mi)
#pragma unroll
      for (int nj = 0; nj < NF; ++nj)
        acc[mi][nj] = __builtin_amdgcn_mfma_f32_16x16x32_bf16(
            af[mi], bfr[nj], acc[mi][nj], 0, 0, 0);
    __syncthreads();   // frag reads done before next stage overwrites
  }

  // Epilogue: C/D layout col=lane&15, row=(lane>>4)*4+reg
#pragma unroll
  for (int nj = 0; nj < NF; ++nj) {
    const int col = n0 + wcol + nj * 16 + (l & 15);
    const float bv = bias ? bias[col] : 0.f;
#pragma unroll
    for (int mi = 0; mi < MF; ++mi) {
#pragma unroll
      for (int q = 0; q < 4; ++q) {
        const int row = m0 + wrow + mi * 16 + (l >> 4) * 4 + q;
        float v = acc[mi][nj][q] + bv;
        if (ACT == 1) v = (v > 20.f) ? v : log1pf(__expf(v));
        if (WF32) Cf[(size_t)row * N + col] = v;
        if (WB16) Cb[(size_t)row * N + col] = f2b1(v);
      }
    }
  }
}

// ---------------------------------------------------------------------------
// Depthwise causal conv (K=4) + SiLU. bf16 in (xz cols < D_INNER), bf16 out.
// 4 channels per thread (us4 vectorized).
// ---------------------------------------------------------------------------
__global__ __launch_bounds__(256) void conv_silu(
    const ushort_t* __restrict__ xzb,
    const float* __restrict__ cw,
    const float* __restrict__ cb,
    ushort_t* __restrict__ xcb)
{
  const int idx = blockIdx.x * 256 + threadIdx.x;   // over NROWS*D_INNER/4
  const int d4 = (idx & (D_INNER / 4 - 1)) * 4;
  const int bt = idx >> 8;
  const int t = bt & (NL - 1);
  const int b = bt >> 10;

  float acc4[4];
  {
    const float4 cbv = *(const float4*)(cb + d4);
    acc4[0] = cbv.x; acc4[1] = cbv.y; acc4[2] = cbv.z; acc4[3] = cbv.w;
  }
  float wv[4][4];
#pragma unroll
  for (int i = 0; i < 4; ++i) {
    const float4 w = *(const float4*)(cw + (size_t)(d4 + i) * KCONV);
    wv[i][0] = w.x; wv[i][1] = w.y; wv[i][2] = w.z; wv[i][3] = w.w;
  }
#pragma unroll
  for (int j = 0; j < KCONV; ++j) {
    const int tt = t - (KCONV - 1) + j;
    if (tt >= 0) {
      const us4 xv = *(const us4*)(xzb + (size_t)(b * NL + tt) * (2 * D_INNER) + d4);
      acc4[0] = fmaf(b2f(xv.x), wv[0][j], acc4[0]);
      acc4[1] = fmaf(b2f(xv.y), wv[1][j], acc4[1]);
      acc4[2] = fmaf(b2f(xv.z), wv[2][j], acc4[2]);
      acc4[3] = fmaf(b2f(xv.w), wv[3][j], acc4[3]);
    }
  }
  us4 o;
#pragma unroll
  for (int i = 0; i < 4; ++i) {
    const float s = acc4[i] / (1.f + __expf(-acc4[i]));
    ((ushort_t*)&o)[i] = f2b1(s);
  }
  *(us4*)(xcb + (size_t)idx * 4) = o;
}

// ---------------------------------------------------------------------------
// Fully fused chunked selective scan: phase1 + carry + phase2 in one kernel.
// Block = 64 chunks x 4 channels (256 threads); grid = (D_INNER/4, NB).
// ---------------------------------------------------------------------------
__global__ __launch_bounds__(256) void scan_fused(
    const ushort_t* __restrict__ dtb,   // bf16 softplus(dt)
    const float* __restrict__ proj,     // fp32, stride 64: [dtl 32 | B 16 | C 16]
    const ushort_t* __restrict__ xcb,   // bf16 conv output
    const ushort_t* __restrict__ xzb,   // bf16 in_proj output (z at col D_INNER+d)
    const float* __restrict__ A_log,
    const float* __restrict__ Dp,
    ushort_t* __restrict__ yb)          // bf16 gated y
{
  __shared__ float S_lds[NCHUNK][4][NSTATE + 1];
  __shared__ float H_lds[NCHUNK][4][NSTATE + 1];
  __shared__ float sdt_lds[NCHUNK][4];

  const int tid = threadIdx.x;
  const int c = tid >> 2;
  const int dl = tid & 3;
  const int d = blockIdx.x * 4 + dl;
  const int b = blockIdx.y;

  float A2[NSTATE];
#pragma unroll
  for (int n = 0; n < NSTATE; ++n)
    A2[n] = -__expf(A_log[d * NSTATE + n]) * LOG2E;

  const int t0 = c * CHUNK;
  float h[NSTATE];
#pragma unroll
  for (int n = 0; n < NSTATE; ++n) h[n] = 0.f;
  float sdt = 0.f;

  // phase 1: local scan from 0, collect chunk summary
  for (int tt = 0; tt < CHUNK; ++tt) {
    const size_t row = (size_t)(b * NL + t0 + tt);
    const float dtv = b2f(dtb[row * D_INNER + d]);
    const float xv = b2f(xcb[row * D_INNER + d]);
    const float* pr = proj + row * 64;
    float Bv[NSTATE];
    *(float4*)(Bv)      = *(const float4*)(pr + 32);
    *(float4*)(Bv + 4)  = *(const float4*)(pr + 36);
    *(float4*)(Bv + 8)  = *(const float4*)(pr + 40);
    *(float4*)(Bv + 12) = *(const float4*)(pr + 44);
    sdt += dtv;
    const float dx = dtv * xv;
#pragma unroll
    for (int n = 0; n < NSTATE; ++n)
      h[n] = fmaf(h[n], exp2f(dtv * A2[n]), dx * Bv[n]);
  }
  sdt_lds[c][dl] = sdt;
#pragma unroll
  for (int n = 0; n < NSTATE; ++n) S_lds[c][dl][n] = h[n];
  __syncthreads();

  // carry: 64 threads own (dl2, n2); serial over 64 chunks in LDS
  if (tid < 64) {
    const int dl2 = tid >> 4;
    const int n2 = tid & 15;
    const float A2n = -__expf(A_log[(blockIdx.x * 4 + dl2) * NSTATE + n2]) * LOG2E;
    float H = 0.f;
    for (int cc = 0; cc < NCHUNK; ++cc) {
      H_lds[cc][dl2][n2] = H;
      H = fmaf(H, exp2f(A2n * sdt_lds[cc][dl2]), S_lds[cc][dl2][n2]);
    }
  }
  __syncthreads();

  // phase 2: re-scan seeded with H_in, emit gated y
#pragma unroll
  for (int n = 0; n < NSTATE; ++n) h[n] = H_lds[c][dl][n];
  const float Dv = Dp[d];

  for (int tt = 0; tt < CHUNK; ++tt) {
    const size_t row = (size_t)(b * NL + t0 + tt);
    const size_t rd = row * D_INNER + d;
    const float dtv = b2f(dtb[rd]);
    const float xv = b2f(xcb[rd]);
    const float* pr = proj + row * 64;
    float Bv[NSTATE], Cv[NSTATE];
    *(float4*)(Bv)      = *(const float4*)(pr + 32);
    *(float4*)(Bv + 4)  = *(const float4*)(pr + 36);
    *(float4*)(Bv + 8)  = *(const float4*)(pr + 40);
    *(float4*)(Bv + 12) = *(const float4*)(pr + 44);
    *(float4*)(Cv)      = *(const float4*)(pr + 48);
    *(float4*)(Cv + 4)  = *(const float4*)(pr + 52);
    *(float4*)(Cv + 8)  = *(const float4*)(pr + 56);
    *(float4*)(Cv + 12) = *(const float4*)(pr + 60);
    const float dx = dtv * xv;
    float accv = 0.f;
#pragma unroll
    for (int n = 0; n < NSTATE; ++n) {
      h[n] = fmaf(h[n], exp2f(dtv * A2[n]), dx * Bv[n]);
      accv = fmaf(h[n], Cv[n], accv);
    }
    const float zv = b2f(xzb[row * (2 * D_INNER) + D_INNER + d]);
    float yv = fmaf(xv, Dv, accv);
    yv *= zv / (1.f + __expf(-zv));
    yb[rd] = f2b1(yv);
  }
}

// ---------------------------------------------------------------------------
// out = LayerNorm(x + res) * w + b. One wave per row. Dual fp32+bf16 write;
// optionally also writes final output rows (t == NL-1) to out2.
// ---------------------------------------------------------------------------
__global__ __launch_bounds__(256) void add_ln(
    const float* __restrict__ x,
    const float* __restrict__ res,
    const float* __restrict__ w,
    const float* __restrict__ bln,
    float* __restrict__ out,
    ushort_t* __restrict__ outb,
    float* __restrict__ out2)
{
  const int wave = threadIdx.x >> 6;
  const int lane = threadIdx.x & 63;
  const int row = blockIdx.x * 4 + wave;
  const float* xr = x + (size_t)row * D_MODEL;
  const float* rr = res + (size_t)row * D_MODEL;

  float v[8];
  float s = 0.f, s2 = 0.f;
#pragma unroll
  for (int i = 0; i < 8; ++i) {
    const float t = xr[lane + i * 64] + rr[lane + i * 64];
    v[i] = t; s += t; s2 = fmaf(t, t, s2);
  }
#pragma unroll
  for (int off = 32; off; off >>= 1) {
    s += __shfl_xor(s, off);
    s2 += __shfl_xor(s2, off);
  }
  const float mean = s * (1.f / D_MODEL);
  const float var = s2 * (1.f / D_MODEL) - mean * mean;
  const float rstd = rsqrtf(var + 1e-5f);
  const bool last_t = (row & (NL - 1)) == (NL - 1);
#pragma unroll
  for (int i = 0; i < 8; ++i) {
    const int c = lane + i * 64;
    const float o = (v[i] - mean) * rstd * w[c] + bln[c];
    out[(size_t)row * D_MODEL + c] = o;
    outb[(size_t)row * D_MODEL + c] = f2b1(o);
    if (out2 && last_t) out2[(size_t)(row >> 10) * D_MODEL + c] = o;
  }
}

// ---------------------------------------------------------------------------
extern "C" void kernel_launch(void* const* d_in, const int* in_sizes, int n_in,
                              void* d_out, int out_size, void* d_ws, size_t ws_size,
                              hipStream_t stream)
{
  const float* x         = (const float*)d_in[0];
  const float* input_w   = (const float*)d_in[1];
  const float* input_b   = (const float*)d_in[2];
  const float* in_proj_w = (const float*)d_in[3];
  const float* in_proj_b = (const float*)d_in[4];
  const float* conv_w    = (const float*)d_in[5];
  const float* conv_b    = (const float*)d_in[6];
  const float* x_proj_w  = (const float*)d_in[7];
  const float* dt_proj_w = (const float*)d_in[8];
  const float* dt_proj_b = (const float*)d_in[9];
  const float* A_log     = (const float*)d_in[10];
  const float* Dp        = (const float*)d_in[11];
  const float* out_proj_w= (const float*)d_in[12];
  const float* out_proj_b= (const float*)d_in[13];
  const float* ln_w      = (const float*)d_in[14];
  const float* ln_b      = (const float*)d_in[15];

  float* p = (float*)d_ws;
  float* h0   = p; p += (size_t)NROWS * D_MODEL;   // fp32 residual stream
  float* h1   = p; p += (size_t)NROWS * D_MODEL;
  float* tmp  = p; p += (size_t)NROWS * D_MODEL;   // out_proj result
  float* proj = p; p += (size_t)NROWS * 64;        // x_proj result (B,C used)
  ushort_t* q = (ushort_t*)p;
  ushort_t* xzb   = q; q += (size_t)NROWS * 2 * D_INNER;  // in_proj out (bf16)
  ushort_t* xcb   = q; q += (size_t)NROWS * D_INNER;      // conv out
  ushort_t* dtbb  = q; q += (size_t)NROWS * D_INNER;      // softplus dt
  ushort_t* projb = q; q += (size_t)NROWS * 64;           // x_proj out bf16
  ushort_t* yb    = q; q += (size_t)NROWS * D_INNER;      // gated y
  ushort_t* hb    = q; q += (size_t)NROWS * D_MODEL;      // bf16 residual copy
  ushort_t* xb    = q; q += (size_t)E0;
  ushort_t* inwb  = q; q += (size_t)E1;
  ushort_t* iwb   = q; q += (size_t)E2;
  ushort_t* xwb   = q; q += (size_t)E3;
  ushort_t* dwb   = q; q += (size_t)E4;
  ushort_t* owb   = q; q += (size_t)E5;

  // one fused conversion dispatch
  cvt_all<<<(ETOT / 4 + 255) / 256, 256, 0, stream>>>(
      x, input_w, in_proj_w, x_proj_w, dt_proj_w, out_proj_w,
      xb, inwb, iwb, xwb, dwb, owb);

  // h0 = x @ input_w^T + input_b  (M=4096,N=512,K=64) -> fp32 + bf16
  gemm_mfma<64, 64, 2, 2, 0, true, true>
      <<<dim3(D_MODEL / 64, NROWS / 64), 256, 0, stream>>>(
      xb, IN_DIM, inwb, input_b, h0, hb, NROWS, D_MODEL, IN_DIM);

  float* hc = h0;
  float* hn = h1;

  for (int l = 0; l < N_LAYERS; ++l) {
    const ushort_t* iw = iwb + (size_t)l * 2 * D_INNER * D_MODEL;
    const float* ib = in_proj_b + (size_t)l * 2 * D_INNER;
    const float* cw = conv_w    + (size_t)l * D_INNER * KCONV;
    const float* cb = conv_b    + (size_t)l * D_INNER;
    const ushort_t* xw = xwb + (size_t)l * 64 * D_INNER;
    const ushort_t* dw = dwb + (size_t)l * D_INNER * DT_RANK;
    const float* db = dt_proj_b + (size_t)l * D_INNER;
    const float* Al = A_log     + (size_t)l * D_INNER * NSTATE;
    const float* Dl = Dp        + (size_t)l * D_INNER;
    const ushort_t* ow = owb + (size_t)l * D_MODEL * D_INNER;
    const float* ob = out_proj_b+ (size_t)l * D_MODEL;
    const float* lw = ln_w      + (size_t)l * D_MODEL;
    const float* lb = ln_b      + (size_t)l * D_MODEL;

    // xz = h @ iw^T + ib  (M=4096,N=2048,K=512) -> bf16 only
    gemm_mfma<128, 128, 4, 4, 0, false, true>
        <<<dim3(2 * D_INNER / 128, NROWS / 128), 256, 0, stream>>>(
        hb, D_MODEL, iw, ib, nullptr, xzb, NROWS, 2 * D_INNER, D_MODEL);

    // xc = silu(conv(xp)) -> bf16
    conv_silu<<<NROWS * D_INNER / 4 / 256, 256, 0, stream>>>(xzb, cw, cb, xcb);

    // proj = xc @ xw^T  (M=4096,N=64,K=1024) -> fp32 + bf16
    gemm_mfma<64, 64, 2, 2, 0, true, true>
        <<<dim3(1, NROWS / 64), 256, 0, stream>>>(
        xcb, D_INNER, xw, nullptr, proj, projb, NROWS, 64, D_INNER);

    // dt = softplus(dtl @ dw^T + db)  (M=4096,N=1024,K=32, A lda=64) -> bf16
    gemm_mfma<128, 128, 4, 4, 1, false, true>
        <<<dim3(D_INNER / 128, NROWS / 128), 256, 0, stream>>>(
        projb, 64, dw, db, nullptr, dtbb, NROWS, D_INNER, DT_RANK);

    // fused chunked selective scan -> bf16 gated y
    scan_fused<<<dim3(D_INNER / 4, NB), 256, 0, stream>>>(
        dtbb, proj, xcb, xzb, Al, Dl, yb);

    // tmp = y @ ow^T + ob  (M=4096,N=512,K=1024) -> fp32
    gemm_mfma<64, 64, 2, 2, 0, true, false>
        <<<dim3(D_MODEL / 64, NROWS / 64), 256, 0, stream>>>(
        yb, D_INNER, ow, ob, tmp, nullptr, NROWS, D_MODEL, D_INNER);

    // hn = LN(tmp + hc); last layer also writes d_out rows (t = NL-1)
    add_ln<<<NROWS / 4, 256, 0, stream>>>(
        tmp, hc, lw, lb, hn, hb,
        (l == N_LAYERS - 1) ? (float*)d_out : nullptr);

    float* t2 = hc; hc = hn; hn = t2;
  }
}

// Round 11
// 599.433 us; speedup vs baseline: 1.0590x; 1.0590x over previous
//
#include <hip/hip_runtime.h>
#include <hip/hip_bf16.h>
#include <cstddef>
#include <cstdint>

// Problem constants
#define NB 4
#define NL 1024
#define IN_DIM 64
#define D_MODEL 512
#define N_LAYERS 3
#define D_INNER 1024
#define NSTATE 16
#define DT_RANK 32
#define KCONV 4
#define NROWS (NB * NL)   // 4096
#define CHUNK 16
#define NCHUNK (NL / CHUNK)  // 64
#define LOG2E 1.4426950408889634f

typedef __attribute__((ext_vector_type(8))) short short8;
typedef __attribute__((ext_vector_type(4))) float f32x4;
typedef __attribute__((ext_vector_type(4))) unsigned short us4;
typedef unsigned short ushort_t;

// float -> bf16 round-to-nearest-even
__device__ __forceinline__ ushort_t f2b1(float x) {
  uint32_t u = __builtin_bit_cast(uint32_t, x);
  u += 0x7fffu + ((u >> 16) & 1u);
  return (ushort_t)(u >> 16);
}
__device__ __forceinline__ float b2f(ushort_t u) {
  return __builtin_bit_cast(float, (uint32_t)u << 16);
}

// async global->LDS, 16B per lane. dst is wave-uniform base; HW adds lane*16.
__device__ __forceinline__ void gload_lds16(const ushort_t* src, short* dst) {
  __builtin_amdgcn_global_load_lds(
      (const __attribute__((address_space(1))) uint32_t*)src,
      (__attribute__((address_space(3))) uint32_t*)dst, 16, 0, 0);
}

// ---------------------------------------------------------------------------
// Fused fp32 -> bf16 conversion of x + all weights (one dispatch).
// ---------------------------------------------------------------------------
#define E0 (NROWS * IN_DIM)                    // x        262144
#define E1 (D_MODEL * IN_DIM)                  // input_w   32768
#define E2 (N_LAYERS * 2 * D_INNER * D_MODEL)  // in_proj 3145728
#define E3 (N_LAYERS * 64 * D_INNER)           // x_proj   196608
#define E4 (N_LAYERS * D_INNER * DT_RANK)      // dt_proj   98304
#define E5 (N_LAYERS * D_MODEL * D_INNER)      // out_proj 1572864
#define ETOT (E0 + E1 + E2 + E3 + E4 + E5)     // 5308416

__global__ __launch_bounds__(256) void cvt_all(
    const float* __restrict__ x, const float* __restrict__ inw,
    const float* __restrict__ ipw, const float* __restrict__ xpw,
    const float* __restrict__ dpw, const float* __restrict__ opw,
    ushort_t* __restrict__ xb, ushort_t* __restrict__ inwb,
    ushort_t* __restrict__ iwb, ushort_t* __restrict__ xwb,
    ushort_t* __restrict__ dwb, ushort_t* __restrict__ owb)
{
  int i = (blockIdx.x * 256 + threadIdx.x) * 4;
  if (i >= ETOT) return;
  const float* src; ushort_t* dst; int off;
  if      (i < E0)                  { src = x;   dst = xb;   off = i; }
  else if (i < E0+E1)               { src = inw; dst = inwb; off = i - E0; }
  else if (i < E0+E1+E2)            { src = ipw; dst = iwb;  off = i - (E0+E1); }
  else if (i < E0+E1+E2+E3)         { src = xpw; dst = xwb;  off = i - (E0+E1+E2); }
  else if (i < E0+E1+E2+E3+E4)      { src = dpw; dst = dwb;  off = i - (E0+E1+E2+E3); }
  else                              { src = opw; dst = owb;  off = i - (E0+E1+E2+E3+E4); }
  const float4 v = *(const float4*)(src + off);
  us4 o;
  o.x = f2b1(v.x); o.y = f2b1(v.y); o.z = f2b1(v.z); o.w = f2b1(v.w);
  *(us4*)(dst + off) = o;
}

// ---------------------------------------------------------------------------
// bf16 MFMA GEMM, m97-style: global_load_lds staging, linear LDS [row][32],
// 2-barrier K-loop. C = A[M,lda] @ W[N,K]^T (+bias)(+softplus).
// 256 threads = 4 waves (2x2). BM=MF*32, BN=NF*32, K%32==0.
// ---------------------------------------------------------------------------
template<int BM, int BN, int MF, int NF, int ACT, bool WF32, bool WB16>
__global__ __launch_bounds__(256) void gemm_mfma(
    const ushort_t* __restrict__ A, int lda,
    const ushort_t* __restrict__ W,
    const float* __restrict__ bias,
    float* __restrict__ Cf, ushort_t* __restrict__ Cb,
    int M, int N, int K)
{
  constexpr int CA = BM / 64;
  constexpr int CB = BN / 64;
  __shared__ __align__(16) short sa[BM * 32];
  __shared__ __align__(16) short sb[BN * 32];

  const int tid = threadIdx.x;
  const int l = tid & 63;
  const int wid = tid >> 6;
  const int wrow = (wid >> 1) * (BM / 2);
  const int wcol = (wid & 1) * (BN / 2);
  const int m0 = blockIdx.y * BM;
  const int n0 = blockIdx.x * BN;

  const int srow = l >> 2;           // row within 16-row group
  const int scol = (l & 3) * 8;      // shorts (16B chunks)

  f32x4 acc[MF][NF] = {};

  for (int k0 = 0; k0 < K; k0 += 32) {
#pragma unroll
    for (int c = 0; c < CA; ++c) {
      short* dst = sa + (c * 4 + wid) * 512;   // wave-uniform, 1024B block
      const ushort_t* src =
          A + (size_t)(m0 + (c * 4 + wid) * 16 + srow) * lda + k0 + scol;
      gload_lds16(src, dst);
    }
#pragma unroll
    for (int c = 0; c < CB; ++c) {
      short* dst = sb + (c * 4 + wid) * 512;
      const ushort_t* src =
          W + (size_t)(n0 + (c * 4 + wid) * 16 + srow) * K + k0 + scol;
      gload_lds16(src, dst);
    }
    __syncthreads();   // drains vmcnt(0): tile in LDS, all waves synced

    short8 af[MF], bfr[NF];
#pragma unroll
    for (int mi = 0; mi < MF; ++mi)
      af[mi] = *(const short8*)(sa + (wrow + mi * 16 + (l & 15)) * 32 + (l >> 4) * 8);
#pragma unroll
    for (int nj = 0; nj < NF; ++nj)
      bfr[nj] = *(const short8*)(sb + (wcol + nj * 16 + (l & 15)) * 32 + (l >> 4) * 8);
#pragma unroll
    for (int mi = 0; mi < MF; ++mi)
#pragma unroll
      for (int nj = 0; nj < NF; ++nj)
        acc[mi][nj] = __builtin_amdgcn_mfma_f32_16x16x32_bf16(
            af[mi], bfr[nj], acc[mi][nj], 0, 0, 0);
    __syncthreads();   // frag reads done before next stage overwrites
  }

  // Epilogue: C/D layout col=lane&15, row=(lane>>4)*4+reg
#pragma unroll
  for (int nj = 0; nj < NF; ++nj) {
    const int col = n0 + wcol + nj * 16 + (l & 15);
    const float bv = bias ? bias[col] : 0.f;
#pragma unroll
    for (int mi = 0; mi < MF; ++mi) {
#pragma unroll
      for (int q = 0; q < 4; ++q) {
        const int row = m0 + wrow + mi * 16 + (l >> 4) * 4 + q;
        float v = acc[mi][nj][q] + bv;
        if (ACT == 1) v = (v > 20.f) ? v : log1pf(__expf(v));
        if (WF32) Cf[(size_t)row * N + col] = v;
        if (WB16) Cb[(size_t)row * N + col] = f2b1(v);
      }
    }
  }
}

// ---------------------------------------------------------------------------
// Depthwise causal conv (K=4) + SiLU. bf16 in (xz cols < D_INNER), bf16 out.
// 4 channels per thread (us4 vectorized).
// ---------------------------------------------------------------------------
__global__ __launch_bounds__(256) void conv_silu(
    const ushort_t* __restrict__ xzb,
    const float* __restrict__ cw,
    const float* __restrict__ cb,
    ushort_t* __restrict__ xcb)
{
  const int idx = blockIdx.x * 256 + threadIdx.x;   // over NROWS*D_INNER/4
  const int d4 = (idx & (D_INNER / 4 - 1)) * 4;
  const int bt = idx >> 8;
  const int t = bt & (NL - 1);
  const int b = bt >> 10;

  float acc4[4];
  {
    const float4 cbv = *(const float4*)(cb + d4);
    acc4[0] = cbv.x; acc4[1] = cbv.y; acc4[2] = cbv.z; acc4[3] = cbv.w;
  }
  float wv[4][4];
#pragma unroll
  for (int i = 0; i < 4; ++i) {
    const float4 w = *(const float4*)(cw + (size_t)(d4 + i) * KCONV);
    wv[i][0] = w.x; wv[i][1] = w.y; wv[i][2] = w.z; wv[i][3] = w.w;
  }
#pragma unroll
  for (int j = 0; j < KCONV; ++j) {
    const int tt = t - (KCONV - 1) + j;
    if (tt >= 0) {
      const us4 xv = *(const us4*)(xzb + (size_t)(b * NL + tt) * (2 * D_INNER) + d4);
      acc4[0] = fmaf(b2f(xv.x), wv[0][j], acc4[0]);
      acc4[1] = fmaf(b2f(xv.y), wv[1][j], acc4[1]);
      acc4[2] = fmaf(b2f(xv.z), wv[2][j], acc4[2]);
      acc4[3] = fmaf(b2f(xv.w), wv[3][j], acc4[3]);
    }
  }
  us4 o;
#pragma unroll
  for (int i = 0; i < 4; ++i) {
    const float s = acc4[i] / (1.f + __expf(-acc4[i]));
    ((ushort_t*)&o)[i] = f2b1(s);
  }
  *(us4*)(xcb + (size_t)idx * 4) = o;
}

// ---------------------------------------------------------------------------
// Chunked selective scan — coalesced d-major 3-kernel structure (R2 geometry,
// bf16 activations). S_loc/H_in layout: [((b*NCHUNK+c)*NSTATE+n)*D_INNER+d].
// ---------------------------------------------------------------------------
__global__ __launch_bounds__(256) void scan_phase1(
    const ushort_t* __restrict__ dtb,
    const float* __restrict__ proj,
    const ushort_t* __restrict__ xcb,
    const float* __restrict__ A_log,
    float* __restrict__ S_loc,
    float* __restrict__ sumdt)
{
  const int d = blockIdx.x * 256 + threadIdx.x;  // 0..1023 (coalesced)
  const int c = blockIdx.y;
  const int b = blockIdx.z;

  float A2[NSTATE];
#pragma unroll
  for (int n = 0; n < NSTATE; ++n)
    A2[n] = -__expf(A_log[d * NSTATE + n]) * LOG2E;

  float h[NSTATE];
#pragma unroll
  for (int n = 0; n < NSTATE; ++n) h[n] = 0.f;
  float sdt = 0.f;

  const int t0 = c * CHUNK;
#pragma unroll 4
  for (int tt = 0; tt < CHUNK; ++tt) {
    const size_t row = (size_t)(b * NL + t0 + tt);
    const float dtv = b2f(dtb[row * D_INNER + d]);
    const float xv = b2f(xcb[row * D_INNER + d]);
    const float* pr = proj + row * 64;
    float Bv[NSTATE];
    *(float4*)(Bv)      = *(const float4*)(pr + 32);
    *(float4*)(Bv + 4)  = *(const float4*)(pr + 36);
    *(float4*)(Bv + 8)  = *(const float4*)(pr + 40);
    *(float4*)(Bv + 12) = *(const float4*)(pr + 44);
    sdt += dtv;
    const float dx = dtv * xv;
#pragma unroll
    for (int n = 0; n < NSTATE; ++n)
      h[n] = fmaf(h[n], exp2f(dtv * A2[n]), dx * Bv[n]);
  }

  const size_t cbase = (size_t)(b * NCHUNK + c);
  sumdt[cbase * D_INNER + d] = sdt;
#pragma unroll
  for (int n = 0; n < NSTATE; ++n)
    S_loc[(cbase * NSTATE + n) * D_INNER + d] = h[n];
}

__global__ __launch_bounds__(256) void scan_carry(
    const float* __restrict__ S_loc,
    const float* __restrict__ sumdt,
    const float* __restrict__ A_log,
    float* __restrict__ H_in)
{
  const int idx = blockIdx.x * 256 + threadIdx.x;  // over NB*NSTATE*D_INNER
  const int d = idx & (D_INNER - 1);
  const int n = (idx >> 10) & (NSTATE - 1);
  const int b = idx >> 14;

  const float A2n = -__expf(A_log[d * NSTATE + n]) * LOG2E;

  float H = 0.f;
  for (int c = 0; c < NCHUNK; ++c) {
    const size_t cbase = (size_t)(b * NCHUNK + c);
    H_in[(cbase * NSTATE + n) * D_INNER + d] = H;
    const float sdt = sumdt[cbase * D_INNER + d];
    H = fmaf(H, exp2f(A2n * sdt), S_loc[(cbase * NSTATE + n) * D_INNER + d]);
  }
}

__global__ __launch_bounds__(256) void scan_phase2(
    const ushort_t* __restrict__ dtb,
    const float* __restrict__ proj,
    const ushort_t* __restrict__ xcb,
    const ushort_t* __restrict__ xzb,   // z at col D_INNER+d
    const float* __restrict__ A_log,
    const float* __restrict__ Dp,
    const float* __restrict__ H_in,
    ushort_t* __restrict__ yb)
{
  const int d = blockIdx.x * 256 + threadIdx.x;
  const int c = blockIdx.y;
  const int b = blockIdx.z;

  float A2[NSTATE];
#pragma unroll
  for (int n = 0; n < NSTATE; ++n)
    A2[n] = -__expf(A_log[d * NSTATE + n]) * LOG2E;

  const size_t cbase = (size_t)(b * NCHUNK + c);
  float h[NSTATE];
#pragma unroll
  for (int n = 0; n < NSTATE; ++n)
    h[n] = H_in[(cbase * NSTATE + n) * D_INNER + d];

  const float Dv = Dp[d];
  const int t0 = c * CHUNK;

#pragma unroll 4
  for (int tt = 0; tt < CHUNK; ++tt) {
    const size_t row = (size_t)(b * NL + t0 + tt);
    const size_t rd = row * D_INNER + d;
    const float dtv = b2f(dtb[rd]);
    const float xv = b2f(xcb[rd]);
    const float* pr = proj + row * 64;
    float Bv[NSTATE], Cv[NSTATE];
    *(float4*)(Bv)      = *(const float4*)(pr + 32);
    *(float4*)(Bv + 4)  = *(const float4*)(pr + 36);
    *(float4*)(Bv + 8)  = *(const float4*)(pr + 40);
    *(float4*)(Bv + 12) = *(const float4*)(pr + 44);
    *(float4*)(Cv)      = *(const float4*)(pr + 48);
    *(float4*)(Cv + 4)  = *(const float4*)(pr + 52);
    *(float4*)(Cv + 8)  = *(const float4*)(pr + 56);
    *(float4*)(Cv + 12) = *(const float4*)(pr + 60);
    const float dx = dtv * xv;
    float accv = 0.f;
#pragma unroll
    for (int n = 0; n < NSTATE; ++n) {
      h[n] = fmaf(h[n], exp2f(dtv * A2[n]), dx * Bv[n]);
      accv = fmaf(h[n], Cv[n], accv);
    }
    const float zv = b2f(xzb[row * (2 * D_INNER) + D_INNER + d]);
    float yv = fmaf(xv, Dv, accv);
    yv *= zv / (1.f + __expf(-zv));
    yb[rd] = f2b1(yv);
  }
}

// ---------------------------------------------------------------------------
// out = LayerNorm(x + res) * w + b. One wave per row. Dual fp32+bf16 write;
// optionally also writes final output rows (t == NL-1) to out2.
// ---------------------------------------------------------------------------
__global__ __launch_bounds__(256) void add_ln(
    const float* __restrict__ x,
    const float* __restrict__ res,
    const float* __restrict__ w,
    const float* __restrict__ bln,
    float* __restrict__ out,
    ushort_t* __restrict__ outb,
    float* __restrict__ out2)
{
  const int wave = threadIdx.x >> 6;
  const int lane = threadIdx.x & 63;
  const int row = blockIdx.x * 4 + wave;
  const float* xr = x + (size_t)row * D_MODEL;
  const float* rr = res + (size_t)row * D_MODEL;

  float v[8];
  float s = 0.f, s2 = 0.f;
#pragma unroll
  for (int i = 0; i < 8; ++i) {
    const float t = xr[lane + i * 64] + rr[lane + i * 64];
    v[i] = t; s += t; s2 = fmaf(t, t, s2);
  }
#pragma unroll
  for (int off = 32; off; off >>= 1) {
    s += __shfl_xor(s, off);
    s2 += __shfl_xor(s2, off);
  }
  const float mean = s * (1.f / D_MODEL);
  const float var = s2 * (1.f / D_MODEL) - mean * mean;
  const float rstd = rsqrtf(var + 1e-5f);
  const bool last_t = (row & (NL - 1)) == (NL - 1);
#pragma unroll
  for (int i = 0; i < 8; ++i) {
    const int c = lane + i * 64;
    const float o = (v[i] - mean) * rstd * w[c] + bln[c];
    out[(size_t)row * D_MODEL + c] = o;
    outb[(size_t)row * D_MODEL + c] = f2b1(o);
    if (out2 && last_t) out2[(size_t)(row >> 10) * D_MODEL + c] = o;
  }
}

// ---------------------------------------------------------------------------
extern "C" void kernel_launch(void* const* d_in, const int* in_sizes, int n_in,
                              void* d_out, int out_size, void* d_ws, size_t ws_size,
                              hipStream_t stream)
{
  const float* x         = (const float*)d_in[0];
  const float* input_w   = (const float*)d_in[1];
  const float* input_b   = (const float*)d_in[2];
  const float* in_proj_w = (const float*)d_in[3];
  const float* in_proj_b = (const float*)d_in[4];
  const float* conv_w    = (const float*)d_in[5];
  const float* conv_b    = (const float*)d_in[6];
  const float* x_proj_w  = (const float*)d_in[7];
  const float* dt_proj_w = (const float*)d_in[8];
  const float* dt_proj_b = (const float*)d_in[9];
  const float* A_log     = (const float*)d_in[10];
  const float* Dp        = (const float*)d_in[11];
  const float* out_proj_w= (const float*)d_in[12];
  const float* out_proj_b= (const float*)d_in[13];
  const float* ln_w      = (const float*)d_in[14];
  const float* ln_b      = (const float*)d_in[15];

  float* p = (float*)d_ws;
  float* h0   = p; p += (size_t)NROWS * D_MODEL;   // fp32 residual stream
  float* h1   = p; p += (size_t)NROWS * D_MODEL;
  float* tmp  = p; p += (size_t)NROWS * D_MODEL;   // out_proj result
  float* proj = p; p += (size_t)NROWS * 64;        // x_proj result (B,C used)
  float* Sloc = p; p += (size_t)NB * NCHUNK * NSTATE * D_INNER; // 4M floats
  float* Hin  = p; p += (size_t)NB * NCHUNK * NSTATE * D_INNER; // 4M floats
  float* sdt  = p; p += (size_t)NB * NCHUNK * D_INNER;          // 256K
  ushort_t* q = (ushort_t*)p;
  ushort_t* xzb   = q; q += (size_t)NROWS * 2 * D_INNER;  // in_proj out (bf16)
  ushort_t* xcb   = q; q += (size_t)NROWS * D_INNER;      // conv out
  ushort_t* dtbb  = q; q += (size_t)NROWS * D_INNER;      // softplus dt
  ushort_t* projb = q; q += (size_t)NROWS * 64;           // x_proj out bf16
  ushort_t* yb    = q; q += (size_t)NROWS * D_INNER;      // gated y
  ushort_t* hb    = q; q += (size_t)NROWS * D_MODEL;      // bf16 residual copy
  ushort_t* xb    = q; q += (size_t)E0;
  ushort_t* inwb  = q; q += (size_t)E1;
  ushort_t* iwb   = q; q += (size_t)E2;
  ushort_t* xwb   = q; q += (size_t)E3;
  ushort_t* dwb   = q; q += (size_t)E4;
  ushort_t* owb   = q; q += (size_t)E5;

  // one fused conversion dispatch
  cvt_all<<<(ETOT / 4 + 255) / 256, 256, 0, stream>>>(
      x, input_w, in_proj_w, x_proj_w, dt_proj_w, out_proj_w,
      xb, inwb, iwb, xwb, dwb, owb);

  // h0 = x @ input_w^T + input_b  (M=4096,N=512,K=64) -> fp32 + bf16
  gemm_mfma<64, 64, 2, 2, 0, true, true>
      <<<dim3(D_MODEL / 64, NROWS / 64), 256, 0, stream>>>(
      xb, IN_DIM, inwb, input_b, h0, hb, NROWS, D_MODEL, IN_DIM);

  float* hc = h0;
  float* hn = h1;

  for (int l = 0; l < N_LAYERS; ++l) {
    const ushort_t* iw = iwb + (size_t)l * 2 * D_INNER * D_MODEL;
    const float* ib = in_proj_b + (size_t)l * 2 * D_INNER;
    const float* cw = conv_w    + (size_t)l * D_INNER * KCONV;
    const float* cb = conv_b    + (size_t)l * D_INNER;
    const ushort_t* xw = xwb + (size_t)l * 64 * D_INNER;
    const ushort_t* dw = dwb + (size_t)l * D_INNER * DT_RANK;
    const float* db = dt_proj_b + (size_t)l * D_INNER;
    const float* Al = A_log     + (size_t)l * D_INNER * NSTATE;
    const float* Dl = Dp        + (size_t)l * D_INNER;
    const ushort_t* ow = owb + (size_t)l * D_MODEL * D_INNER;
    const float* ob = out_proj_b+ (size_t)l * D_MODEL;
    const float* lw = ln_w      + (size_t)l * D_MODEL;
    const float* lb = ln_b      + (size_t)l * D_MODEL;

    // xz = h @ iw^T + ib  (M=4096,N=2048,K=512) -> bf16 only
    gemm_mfma<128, 128, 4, 4, 0, false, true>
        <<<dim3(2 * D_INNER / 128, NROWS / 128), 256, 0, stream>>>(
        hb, D_MODEL, iw, ib, nullptr, xzb, NROWS, 2 * D_INNER, D_MODEL);

    // xc = silu(conv(xp)) -> bf16
    conv_silu<<<NROWS * D_INNER / 4 / 256, 256, 0, stream>>>(xzb, cw, cb, xcb);

    // proj = xc @ xw^T  (M=4096,N=64,K=1024) -> fp32 + bf16
    gemm_mfma<64, 64, 2, 2, 0, true, true>
        <<<dim3(1, NROWS / 64), 256, 0, stream>>>(
        xcb, D_INNER, xw, nullptr, proj, projb, NROWS, 64, D_INNER);

    // dt = softplus(dtl @ dw^T + db)  (M=4096,N=1024,K=32, A lda=64) -> bf16
    gemm_mfma<128, 128, 4, 4, 1, false, true>
        <<<dim3(D_INNER / 128, NROWS / 128), 256, 0, stream>>>(
        projb, 64, dw, db, nullptr, dtbb, NROWS, D_INNER, DT_RANK);

    // coalesced chunked scan (3 kernels)
    scan_phase1<<<dim3(D_INNER / 256, NCHUNK, NB), 256, 0, stream>>>(
        dtbb, proj, xcb, Al, Sloc, sdt);
    scan_carry<<<(NB * NSTATE * D_INNER) / 256, 256, 0, stream>>>(
        Sloc, sdt, Al, Hin);
    scan_phase2<<<dim3(D_INNER / 256, NCHUNK, NB), 256, 0, stream>>>(
        dtbb, proj, xcb, xzb, Al, Dl, Hin, yb);

    // tmp = y @ ow^T + ob  (M=4096,N=512,K=1024) -> fp32, 128x128 tile
    gemm_mfma<128, 128, 4, 4, 0, true, false>
        <<<dim3(D_MODEL / 128, NROWS / 128), 256, 0, stream>>>(
        yb, D_INNER, ow, ob, tmp, nullptr, NROWS, D_MODEL, D_INNER);

    // hn = LN(tmp + hc); last layer also writes d_out rows (t = NL-1)
    add_ln<<<NROWS / 4, 256, 0, stream>>>(
        tmp, hc, lw, lb, hn, hb,
        (l == N_LAYERS - 1) ? (float*)d_out : nullptr);

    float* t2 = hc; hc = hn; hn = t2;
  }
}